// Round 1
// baseline (1872.421 us; speedup 1.0000x reference)
//
#include <hip/hip_runtime.h>
#include <math.h>

#define NB 4
#define NS 1024
#define ND 1024
#define NH 16
#define NDH 64

// ---------------------------------------------------------------------------
// Kernel 1: q projection with variance propagation.
//   q     = x @ Wm^T
//   var_q = var_x @ (Wv + Wm^2)^T + x^2 @ Wv^T
// Output written in [B,H,S,DH] layout into workspace.
// ---------------------------------------------------------------------------
__global__ __launch_bounds__(256)
void qproj_kernel(const float* __restrict__ x, const float* __restrict__ vx,
                  const float* __restrict__ Wm, const float* __restrict__ Wv,
                  float* __restrict__ q_ws, float* __restrict__ vq_ws)
{
    __shared__ float sX[16][64];
    __shared__ float sVX[16][64];
    __shared__ float sWM[16][64];
    __shared__ float sWV[16][64];

    const int tid = threadIdx.x;
    const int tn = tid & 15;
    const int tm = tid >> 4;
    const int n0 = blockIdx.x * 64;
    const int m0 = blockIdx.y * 64;
    const int lr = tid >> 2;
    const int lk = (tid & 3) << 2;

    float accq[4][4] = {};
    float accv[4][4] = {};

    const float* xrow  = x  + (size_t)(m0 + lr) * ND + lk;
    const float* vrow  = vx + (size_t)(m0 + lr) * ND + lk;
    const float* wmrow = Wm + (size_t)(n0 + lr) * ND + lk;
    const float* wvrow = Wv + (size_t)(n0 + lr) * ND + lk;

    for (int kt = 0; kt < ND / 16; ++kt) {
        const float4 xa  = *(const float4*)(xrow  + kt * 16);
        const float4 va  = *(const float4*)(vrow  + kt * 16);
        const float4 wm4 = *(const float4*)(wmrow + kt * 16);
        const float4 wv4 = *(const float4*)(wvrow + kt * 16);
        __syncthreads();
        sX [lk+0][lr] = xa.x;  sX [lk+1][lr] = xa.y;  sX [lk+2][lr] = xa.z;  sX [lk+3][lr] = xa.w;
        sVX[lk+0][lr] = va.x;  sVX[lk+1][lr] = va.y;  sVX[lk+2][lr] = va.z;  sVX[lk+3][lr] = va.w;
        sWM[lk+0][lr] = wm4.x; sWM[lk+1][lr] = wm4.y; sWM[lk+2][lr] = wm4.z; sWM[lk+3][lr] = wm4.w;
        sWV[lk+0][lr] = wv4.x; sWV[lk+1][lr] = wv4.y; sWV[lk+2][lr] = wv4.z; sWV[lk+3][lr] = wv4.w;
        __syncthreads();
        #pragma unroll
        for (int kk = 0; kk < 16; ++kk) {
            float ax[4], av[4], bm[4], bv[4], bw2[4];
            *(float4*)ax = *(const float4*)&sX [kk][tm << 2];
            *(float4*)av = *(const float4*)&sVX[kk][tm << 2];
            *(float4*)bm = *(const float4*)&sWM[kk][tn << 2];
            *(float4*)bv = *(const float4*)&sWV[kk][tn << 2];
            #pragma unroll
            for (int j = 0; j < 4; ++j) bw2[j] = fmaf(bm[j], bm[j], bv[j]);
            #pragma unroll
            for (int i = 0; i < 4; ++i) {
                const float xx = ax[i] * ax[i];
                #pragma unroll
                for (int j = 0; j < 4; ++j) {
                    accq[i][j] = fmaf(ax[i], bm[j], accq[i][j]);
                    accv[i][j] = fmaf(av[i], bw2[j], fmaf(xx, bv[j], accv[i][j]));
                }
            }
        }
    }

    const int h = blockIdx.x;
    #pragma unroll
    for (int i = 0; i < 4; ++i) {
        const int m = m0 + (tm << 2) + i;
        const int b = m >> 10;
        const int srow = m & 1023;
        const size_t o = (((size_t)b * NH + h) * NS + srow) * NDH + (tn << 2);
        *(float4*)(q_ws  + o) = make_float4(accq[i][0], accq[i][1], accq[i][2], accq[i][3]);
        *(float4*)(vq_ws + o) = make_float4(accv[i][0], accv[i][1], accv[i][2], accv[i][3]);
    }
}

// ---------------------------------------------------------------------------
// Kernel 2: fused causal attention with VDP variance propagation (online
// softmax, flash-style, no SxS materialization).
// ---------------------------------------------------------------------------
__global__ __launch_bounds__(512)
void attn_vdp_kernel(const float* __restrict__ q_ws, const float* __restrict__ vq_ws,
                     const float* __restrict__ K,  const float* __restrict__ VK,
                     const float* __restrict__ Vv, const float* __restrict__ VV,
                     const float* __restrict__ x,
                     float* __restrict__ out0, float* __restrict__ out1)
{
    __shared__ float sQ [64][128];
    __shared__ float sKT[64][128];
    __shared__ float sVt[64][128];
    __shared__ float sC [8][8][128];

    const int tid  = threadIdx.x;
    const int wv   = tid >> 6;
    const int lane = tid & 63;

    const int blk = blockIdx.x;
    const int qb  = blk & 15;
    const int bh  = blk >> 4;
    const int b   = bh >> 4;
    const int h   = bh & 15;
    const size_t kvbase = (size_t)bh * NS * NDH;
    const int row0 = qb * 64;

    #pragma unroll
    for (int it = 0; it < 8; ++it) {
        const int pos = tid + it * 512;
        const int r = pos >> 6, d = pos & 63;
        const size_t g = kvbase + (size_t)(row0 + r) * NDH + d;
        *(float2*)&sQ[r][d << 1] = make_float2(q_ws[g], vq_ws[g]);
    }

    float m_[8], Z_[8], S2_[8], N1[8], N2w[8], N2uw[8], N3uw[8], N2vv[8];
    #pragma unroll
    for (int r = 0; r < 8; ++r) {
        m_[r] = -INFINITY; Z_[r] = 0.f; S2_[r] = 0.f;
        N1[r] = 0.f; N2w[r] = 0.f; N2uw[r] = 0.f; N3uw[r] = 0.f; N2vv[r] = 0.f;
    }

    const int r0 = wv << 3;
    const int nt = qb + 1;
    for (int t = 0; t < nt; ++t) {
        const int j0 = t << 6;
        __syncthreads();
        #pragma unroll
        for (int it = 0; it < 8; ++it) {
            const int pos = tid + it * 512;
            const int jr = pos >> 6, d = pos & 63;
            const size_t g = kvbase + (size_t)(j0 + jr) * NDH + d;
            *(float2*)&sVt[jr][d << 1] = make_float2(Vv[g], VV[g]);
            *(float2*)&sKT[d][(jr ^ d) << 1] = make_float2(K[g], VK[g]);
        }
        __syncthreads();

        float a_[8] = {}, u_[8] = {};
        #pragma unroll 4
        for (int dh = 0; dh < 64; ++dh) {
            const float2 kp = *(const float2*)&sKT[dh][(lane ^ dh) << 1];
            const float kk2 = fmaf(kp.x, kp.x, kp.y);
            #pragma unroll
            for (int r = 0; r < 8; ++r) {
                const float2 qp = *(const float2*)&sQ[r0 + r][dh << 1];
                a_[r] = fmaf(qp.x, kp.x, a_[r]);
                u_[r] = fmaf(qp.y, kk2, fmaf(qp.x * qp.x, kp.y, u_[r]));
            }
        }
        #pragma unroll
        for (int r = 0; r < 8; ++r) {
            const int irow = row0 + r0 + r;
            float a = a_[r] * 0.03125f;
            const float u = u_[r] * 0.0009765625f;
            if (j0 + lane > irow) a = -INFINITY;
            float tmax = a;
            #pragma unroll
            for (int s_ = 32; s_; s_ >>= 1) tmax = fmaxf(tmax, __shfl_xor(tmax, s_));
            const float mnew = fmaxf(m_[r], tmax);
            const float e  = __expf(a - mnew);
            const float s1 = __expf(m_[r] - mnew);
            m_[r] = mnew;
            float Zt = e, S2t = e * e * u;
            #pragma unroll
            for (int s_ = 32; s_; s_ >>= 1) { Zt += __shfl_xor(Zt, s_); S2t += __shfl_xor(S2t, s_); }
            const float s2 = s1 * s1, s3 = s2 * s1;
            Z_[r]  = fmaf(Z_[r],  s1, Zt);
            S2_[r] = fmaf(S2_[r], s2, S2t);
            N1[r] *= s1; N2w[r] *= s2; N2uw[r] *= s2; N3uw[r] *= s3; N2vv[r] *= s2;
            *(float2*)&sC[wv][r][lane << 1] = make_float2(e, u);
        }
        __syncthreads();

        #pragma unroll 4
        for (int j = 0; j < 64; ++j) {
            const float2 vp = *(const float2*)&sVt[j][lane << 1];
            const float w = fmaf(vp.x, vp.x, vp.y);
            #pragma unroll
            for (int r = 0; r < 8; ++r) {
                const float2 cp = *(const float2*)&sC[wv][r][j << 1];
                const float e = cp.x, uu = cp.y;
                const float c2  = e * e;
                const float c2u = c2 * uu;
                const float c3u = c2u * e;
                N1[r]   = fmaf(e,   vp.x, N1[r]);
                N2w[r]  = fmaf(c2,  w,    N2w[r]);
                N2uw[r] = fmaf(c2u, w,    N2uw[r]);
                N3uw[r] = fmaf(c3u, w,    N3uw[r]);
                N2vv[r] = fmaf(c2,  vp.y, N2vv[r]);
            }
        }
    }

    #pragma unroll
    for (int r = 0; r < 8; ++r) {
        const int irow = row0 + r0 + r;
        const float rZ  = 1.0f / Z_[r];
        const float rZ2 = rZ * rZ;
        const float s   = S2_[r] * rZ2;
        const float Om  = N1[r] * rZ;
        const float Vo  = rZ2 * (fmaf(s, N2w[r], N2uw[r] + N2vv[r])) - 2.0f * rZ2 * rZ * N3uw[r];
        const size_t o = ((size_t)b * NS + irow) * ND + (h << 6) + lane;
        out0[o] = x[o] + Om;
        out1[o] = Vo;
    }
}

extern "C" void kernel_launch(void* const* d_in, const int* in_sizes, int n_in,
                              void* d_out, int out_size, void* d_ws, size_t ws_size,
                              hipStream_t stream)
{
    (void)in_sizes; (void)n_in; (void)out_size; (void)ws_size;
    const float* x  = (const float*)d_in[0];
    const float* vx = (const float*)d_in[1];
    const float* K  = (const float*)d_in[2];
    const float* VK = (const float*)d_in[3];
    const float* Vv = (const float*)d_in[4];
    const float* VV = (const float*)d_in[5];
    const float* Wm = (const float*)d_in[6];
    const float* Wv = (const float*)d_in[7];

    float* out0 = (float*)d_out;
    float* out1 = out0 + (size_t)NB * NS * ND;
    float* q_ws  = (float*)d_ws;
    float* vq_ws = q_ws + (size_t)NB * NH * NS * NDH;

    dim3 g1(ND / 64, (NB * NS) / 64);
    qproj_kernel<<<g1, 256, 0, stream>>>(x, vx, Wm, Wv, q_ws, vq_ws);
    attn_vdp_kernel<<<NB * NH * (NS / 64), 512, 0, stream>>>(q_ws, vq_ws, K, VK, Vv, VV, x, out0, out1);
}